// Round 5
// baseline (202.085 us; speedup 1.0000x reference)
//
#include <hip/hip_runtime.h>
#include <hip/hip_bf16.h>

typedef __attribute__((ext_vector_type(8))) short short8;
typedef __attribute__((ext_vector_type(16))) float f32x16;

#define LL 16
#define NP3 23
#define NE 10
#define NC 128
#define KI 24            // fused K stride per i: 23 U3 slots + 1 U2/zero slot
#define NSK 24           // K-steps (384/16) per N-tile
#define NT 8             // N-tiles of 32 cols (256 total)
#define MB 128           // rows per block (= one b)
#define THREADS 256
#define TILE_B 24576     // bytes per B N-tile: 24 frags * 64 lanes * 16 B

static __device__ __forceinline__ short f2bs(float f) {
    __hip_bfloat16 h = __float2bfloat16(f);
    short s;
    __builtin_memcpy(&s, &h, 2);
    return s;
}

// ---- kernel 1: pack U3/U2 -> fragment-major bf16 B for 32x32x16 ----
// frag g = t*24+s ; lane: col = t*32+(lane&31), k = s*16+(lane>>5)*8+j
// B[n][K], K = i*24+kk : kk<23 ? U3[n][i][kk] : (i<4 ? U2[n][i] : 0)
__global__ void build_B(const float* __restrict__ U3, const float* __restrict__ U2,
                        __hip_bfloat16* __restrict__ Bf) {
    int g = blockIdx.x;              // 0..191
    int t = g / NSK, s = g % NSK;
    int lane = threadIdx.x;
    int col  = t * 32 + (lane & 31);
    int hi   = lane >> 5;
    short8 v;
#pragma unroll
    for (int j = 0; j < 8; ++j) {
        int K = s * 16 + hi * 8 + j;
        int i = K / KI, kk = K - i * KI;
        float f;
        if (kk < NP3)    f = U3[((size_t)col * LL + i) * NP3 + kk];
        else if (i < 4)  f = U2[col * 4 + i];
        else             f = 0.f;
        v[j] = f2bs(f);
    }
    *reinterpret_cast<short8*>(Bf + ((size_t)g * 64 + lane) * 8) = v;
}

// A-build: s,j unrolled -> K compile-time -> register-indexed xr/wr fold statically
#define BUILD_A(HIOFF)                                                        \
    _Pragma("unroll")                                                         \
    for (int s = 0; s < NSK; ++s) {                                           \
        short8 av;                                                            \
        _Pragma("unroll")                                                     \
        for (int j = 0; j < 8; ++j) {                                         \
            const int K  = s * 16 + (HIOFF) + j;                              \
            const int i  = K / KI;                                            \
            const int kk = K - i * KI;                                        \
            float f = (kk < NP3) ? xr[i] * wr[kk]                             \
                                 : ((i < 4) ? w2r[i] : 0.f);                  \
            av[j] = f2bs(f);                                                  \
        }                                                                     \
        A[s] = av;                                                            \
    }

// async global->LDS, 16B per lane (linear dest: wave-uniform base + lane*16)
static __device__ __forceinline__ void gload_lds16(const void* g, void* l) {
    __builtin_amdgcn_global_load_lds((const __attribute__((address_space(1))) void*)g,
                                     (__attribute__((address_space(3))) void*)l, 16, 0, 0);
}

// ---- kernel 2: fused contraction, A in registers, B double-buffered in LDS ----
__global__ __launch_bounds__(THREADS, 2)
void contract_k(const float* __restrict__ x, const float* __restrict__ y,
                const float* __restrict__ W3, const float* __restrict__ W2,
                const float* __restrict__ W1, const float* __restrict__ U1,
                const __hip_bfloat16* __restrict__ Bf, float* __restrict__ out) {
    __shared__ __align__(16) char Bs[2][TILE_B];             // 48 KB double buffer
    __shared__ float xs[MB][17];
    __shared__ float wys[MB][29];   // 0..22 Wy3, 23..26 Wy2, 27 Wy1, 28 du=U1.x

    const int tid = threadIdx.x;
    const int m0  = blockIdx.x * MB;
    const int b   = blockIdx.x;     // MB == NC -> one b per block

#define STAGE(tile, buf)                                                      \
    {                                                                         \
        const char* gsrc = (const char*)Bf + (size_t)(tile) * TILE_B + tid * 16; \
        char* ldst = &Bs[buf][tid * 16];                                      \
        _Pragma("unroll")                                                     \
        for (int j = 0; j < 6; ++j)                                           \
            gload_lds16(gsrc + j * 4096, ldst + j * 4096);                    \
    }

    // issue B tiles 0 and 1 immediately (land under the prologue)
    STAGE(0, 0);
    STAGE(1, 1);

    // stage x rows (coalesced)
    for (int idx = tid; idx < MB * LL; idx += THREADS)
        xs[idx >> 4][idx & 15] = x[(size_t)m0 * LL + idx];
    __syncthreads();                 // xs visible (compiler drains vmcnt here too)

    // Wy = y.W, coalesced over c (=r); plus du[r] = U1 . x[r]
    float yv[NE];
#pragma unroll
    for (int e = 0; e < NE; ++e) yv[e] = y[(size_t)b * NE + e];

    for (int u = tid; u < 29 * MB; u += THREADS) {
        int idx = u >> 7, r = u & (MB - 1);
        float s = 0.f;
        if (idx < NP3) {
#pragma unroll
            for (int e = 0; e < NE; ++e) s += yv[e] * W3[(e * NP3 + idx) * NC + r];
        } else if (idx < 27) {
#pragma unroll
            for (int e = 0; e < NE; ++e) s += yv[e] * W2[(e * 4 + (idx - NP3)) * NC + r];
        } else if (idx == 27) {
#pragma unroll
            for (int e = 0; e < NE; ++e) s += yv[e] * W1[e * NC + r];
        } else {
#pragma unroll
            for (int w = 0; w < LL; ++w) s += U1[w] * xs[r][w];
        }
        wys[r][idx] = s;
    }
    __syncthreads();

    // per-lane geometry
    const int lane = tid & 63;
    const int wb   = tid >> 6;          // wave id: rows [wb*32, wb*32+32)
    const int l31  = lane & 31;
    const int hi   = lane >> 5;
    const int bsel = l31 >> 4;          // which w within a 32-col tile
    const int arow = wb * 32 + l31;     // this lane's A row

    // build A fragments (96 VGPR): A[s] holds Z[arow][s*16 + hi*8 .. +8]
    short8 A[NSK];
    {
        float xr[LL], wr[NP3], w2r[4];
#pragma unroll
        for (int i = 0; i < LL; ++i) xr[i] = xs[arow][i];
#pragma unroll
        for (int k = 0; k < NP3; ++k) wr[k] = wys[arow][k];
#pragma unroll
        for (int i = 0; i < 4; ++i) w2r[i] = wys[arow][NP3 + i];
        if (hi == 0) { BUILD_A(0) } else { BUILD_A(8) }
    }

    // xx[q] = x[row(q)][col&15]  (col&15 == lane&15 for every tile)
    float xx[16];
#pragma unroll
    for (int q = 0; q < 16; ++q) {
        int rowq = (wb << 5) + (q & 3) + ((q >> 2) << 3) + (hi << 2);
        xx[q] = xs[rowq][lane & 15];
    }

    float acc_out[16];
#pragma unroll
    for (int q = 0; q < 16; ++q) acc_out[q] = 0.f;

    // main loop: tile t from Bs[t&1] via ds_read_b128; prefetch t+2 after barrier
#pragma unroll
    for (int t = 0; t < NT; ++t) {
        const int cur = t & 1;
        f32x16 acc;
#pragma unroll
        for (int q = 0; q < 16; ++q) acc[q] = 0.f;
#pragma unroll
        for (int s = 0; s < NSK; ++s) {
            short8 bfrag = *reinterpret_cast<const short8*>(&Bs[cur][(s * 64 + lane) * 16]);
            acc = __builtin_amdgcn_mfma_f32_32x32x16_bf16(A[s], bfrag, acc, 0, 0, 0);
        }
        // fold tile t: col = t*32 + l31 ; w = 2t + bsel ; x = lane&15
#pragma unroll
        for (int q = 0; q < 16; ++q) {
            int rowq = (wb << 5) + (q & 3) + ((q >> 2) << 3) + (hi << 2);
            float xw = xs[rowq][2 * t + bsel];
            acc_out[q] += acc[q] * xx[q] * xw;
        }
        __syncthreads();               // all waves done with Bs[cur]; prior stage landed
        if (t + 2 < NT) STAGE(t + 2, cur);
    }

    // butterfly over the 32-lane half (rows depend on (q,hi) only), then write
#pragma unroll
    for (int q = 0; q < 16; ++q) {
        float v = acc_out[q];
        v += __shfl_xor(v, 1);
        v += __shfl_xor(v, 2);
        v += __shfl_xor(v, 4);
        v += __shfl_xor(v, 8);
        v += __shfl_xor(v, 16);
        if (l31 == 0) {
            int rowq = (wb << 5) + (q & 3) + ((q >> 2) << 3) + (hi << 2);
            out[m0 + rowq] = v + wys[rowq][27] * wys[rowq][28];
        }
    }
#undef STAGE
}

extern "C" void kernel_launch(void* const* d_in, const int* in_sizes, int n_in,
                              void* d_out, int out_size, void* d_ws, size_t ws_size,
                              hipStream_t stream) {
    const float* x  = (const float*)d_in[0];
    const float* y  = (const float*)d_in[1];
    const float* U3 = (const float*)d_in[2];
    const float* U2 = (const float*)d_in[3];
    const float* U1 = (const float*)d_in[4];
    const float* W3 = (const float*)d_in[5];
    const float* W2 = (const float*)d_in[6];
    const float* W1 = (const float*)d_in[7];
    __hip_bfloat16* Bf = (__hip_bfloat16*)d_ws;   // 192 frags * 64 lanes * 8 bf16 * 2B = 196608 B

    build_B<<<NT * NSK, 64, 0, stream>>>(U3, U2, Bf);
    contract_k<<<2048, THREADS, 0, stream>>>(x, y, W3, W2, W1, U1, Bf, (float*)d_out);
}

// Round 6
// 144.993 us; speedup vs baseline: 1.3938x; 1.3938x over previous
//
#include <hip/hip_runtime.h>
#include <hip/hip_bf16.h>

typedef __attribute__((ext_vector_type(8))) short short8;
typedef __attribute__((ext_vector_type(16))) float f32x16;
typedef __attribute__((ext_vector_type(4))) float f32x4;

#define LL 16
#define NP3 23
#define NE 10
#define NC 128
#define KI 24            // fused K stride per i: 23 U3 slots + 1 U2/zero slot
#define NSK 24           // K-steps (384/16) per N-tile
#define NT 8             // N-tiles of 32 cols (256 total)
#define MB 128           // rows per block (= one b)
#define THREADS 256
#define TILE_B 24576     // bytes per B N-tile: 24 frags * 64 lanes * 16 B

static __device__ __forceinline__ short f2bs(float f) {
    __hip_bfloat16 h = __float2bfloat16(f);
    short s;
    __builtin_memcpy(&s, &h, 2);
    return s;
}

// ---- kernel 1: pack U3/U2 -> fragment-major bf16 B for 32x32x16 ----
// frag g = t*24+s ; lane: col = t*32+(lane&31), k = s*16+(lane>>5)*8+j
// B[n][K], K = i*24+kk : kk<23 ? U3[n][i][kk] : (i<4 ? U2[n][i] : 0)
__global__ void build_B(const float* __restrict__ U3, const float* __restrict__ U2,
                        __hip_bfloat16* __restrict__ Bf) {
    int g = blockIdx.x;              // 0..191
    int t = g / NSK, s = g % NSK;
    int lane = threadIdx.x;
    int col  = t * 32 + (lane & 31);
    int hi   = lane >> 5;
    short8 v;
#pragma unroll
    for (int j = 0; j < 8; ++j) {
        int K = s * 16 + hi * 8 + j;
        int i = K / KI, kk = K - i * KI;
        float f;
        if (kk < NP3)    f = U3[((size_t)col * LL + i) * NP3 + kk];
        else if (i < 4)  f = U2[col * 4 + i];
        else             f = 0.f;
        v[j] = f2bs(f);
    }
    *reinterpret_cast<short8*>(Bf + ((size_t)g * 64 + lane) * 8) = v;
}

// A-build: s,j unrolled -> K compile-time -> register-indexed xr/wr fold statically
#define BUILD_A(HIOFF)                                                        \
    _Pragma("unroll")                                                         \
    for (int s = 0; s < NSK; ++s) {                                           \
        short8 av;                                                            \
        _Pragma("unroll")                                                     \
        for (int j = 0; j < 8; ++j) {                                         \
            const int K  = s * 16 + (HIOFF) + j;                              \
            const int i  = K / KI;                                            \
            const int kk = K - i * KI;                                        \
            float f = (kk < NP3) ? xr[i] * wr[kk]                             \
                                 : ((i < 4) ? w2r[i] : 0.f);                  \
            av[j] = f2bs(f);                                                  \
        }                                                                     \
        A[s] = av;                                                            \
    }

// ---- kernel 2: fused contraction, A in registers, B reg-staged -> LDS dbuf ----
__global__ __launch_bounds__(THREADS, 2)
void contract_k(const float* __restrict__ x, const float* __restrict__ y,
                const float* __restrict__ W3, const float* __restrict__ W2,
                const float* __restrict__ W1, const float* __restrict__ U1,
                const __hip_bfloat16* __restrict__ Bf, float* __restrict__ out) {
    __shared__ __align__(16) char Bs[2][TILE_B];             // 48 KB double buffer
    __shared__ float xs[MB][17];
    __shared__ float wys[MB][29];   // 0..22 Wy3, 23..26 Wy2, 27 Wy1, 28 du=U1.x

    const int tid = threadIdx.x;
    const int m0  = blockIdx.x * MB;
    const int b   = blockIdx.x;     // MB == NC -> one b per block

    // reg-staged transport: L2-cached flat loads -> regs -> ds_write_b128
    const f32x4* gB = reinterpret_cast<const f32x4*>(Bf);
    f32x4 st[6];
#define LOADT(t)                                                              \
    {                                                                         \
        const f32x4* p = gB + (size_t)(t) * (TILE_B / 16) + tid;              \
        _Pragma("unroll")                                                     \
        for (int j = 0; j < 6; ++j) st[j] = p[j * 256];                       \
    }
#define WRITET(buf)                                                           \
    {                                                                         \
        f32x4* q = reinterpret_cast<f32x4*>(&Bs[buf][0]) + tid;               \
        _Pragma("unroll")                                                     \
        for (int j = 0; j < 6; ++j) q[j * 256] = st[j];                       \
    }

    LOADT(0);                        // in flight under the whole prologue

    // stage x rows (coalesced)
    for (int idx = tid; idx < MB * LL; idx += THREADS)
        xs[idx >> 4][idx & 15] = x[(size_t)m0 * LL + idx];
    __syncthreads();                 // xs visible for du term

    // Wy = y.W, coalesced over c (=r); plus du[r] = U1 . x[r]
    float yv[NE];
#pragma unroll
    for (int e = 0; e < NE; ++e) yv[e] = y[(size_t)b * NE + e];

    for (int u = tid; u < 29 * MB; u += THREADS) {
        int idx = u >> 7, r = u & (MB - 1);
        float s = 0.f;
        if (idx < NP3) {
#pragma unroll
            for (int e = 0; e < NE; ++e) s += yv[e] * W3[(e * NP3 + idx) * NC + r];
        } else if (idx < 27) {
#pragma unroll
            for (int e = 0; e < NE; ++e) s += yv[e] * W2[(e * 4 + (idx - NP3)) * NC + r];
        } else if (idx == 27) {
#pragma unroll
            for (int e = 0; e < NE; ++e) s += yv[e] * W1[e * NC + r];
        } else {
#pragma unroll
            for (int w = 0; w < LL; ++w) s += U1[w] * xs[r][w];
        }
        wys[r][idx] = s;
    }
    __syncthreads();

    // tile 0 -> LDS, start tile 1 load; A-build overlaps the latency
    WRITET(0);
    LOADT(1);

    // per-lane geometry
    const int lane = tid & 63;
    const int wb   = tid >> 6;          // wave id: rows [wb*32, wb*32+32)
    const int l31  = lane & 31;
    const int hi   = lane >> 5;
    const int bsel = l31 >> 4;          // which w within a 32-col tile
    const int arow = wb * 32 + l31;     // this lane's A row

    // build A fragments (96 VGPR): A[s] holds Z[arow][s*16 + hi*8 .. +8]
    short8 A[NSK];
    {
        float xr[LL], wr[NP3], w2r[4];
#pragma unroll
        for (int i = 0; i < LL; ++i) xr[i] = xs[arow][i];
#pragma unroll
        for (int k = 0; k < NP3; ++k) wr[k] = wys[arow][k];
#pragma unroll
        for (int i = 0; i < 4; ++i) w2r[i] = wys[arow][NP3 + i];
        if (hi == 0) { BUILD_A(0) } else { BUILD_A(8) }
    }

    // xx[q] = x[row(q)][col&15]  (col&15 == lane&15 for every tile)
    float xx[16];
#pragma unroll
    for (int q = 0; q < 16; ++q) {
        int rowq = (wb << 5) + (q & 3) + ((q >> 2) << 3) + (hi << 2);
        xx[q] = xs[rowq][lane & 15];
    }

    float acc_out[16];
#pragma unroll
    for (int q = 0; q < 16; ++q) acc_out[q] = 0.f;

    __syncthreads();                 // tile 0 visible to all waves

    // main loop: 1 barrier/tile; write t+1 (other buffer), refill regs with t+2,
    // compute t. MFMA window (~768 SIMD-cyc) hides the L2 latency of LOADT.
#pragma unroll
    for (int t = 0; t < NT; ++t) {
        const int cur = t & 1;
        if (t + 1 < NT) WRITET((t + 1) & 1);
        if (t + 2 < NT) LOADT(t + 2);

        f32x16 acc;
#pragma unroll
        for (int q = 0; q < 16; ++q) acc[q] = 0.f;
#pragma unroll
        for (int s = 0; s < NSK; ++s) {
            short8 bfrag = *reinterpret_cast<const short8*>(&Bs[cur][(s * 64 + lane) * 16]);
            acc = __builtin_amdgcn_mfma_f32_32x32x16_bf16(A[s], bfrag, acc, 0, 0, 0);
        }
        // fold tile t: col = t*32 + l31 ; w = 2t + bsel ; x = lane&15
#pragma unroll
        for (int q = 0; q < 16; ++q) {
            int rowq = (wb << 5) + (q & 3) + ((q >> 2) << 3) + (hi << 2);
            float xw = xs[rowq][2 * t + bsel];
            acc_out[q] += acc[q] * xx[q] * xw;
        }
        __syncthreads();             // readers done with Bs[cur]; writes of t+1 visible
    }

    // butterfly over the 32-lane half (rows depend on (q,hi) only), then write
#pragma unroll
    for (int q = 0; q < 16; ++q) {
        float v = acc_out[q];
        v += __shfl_xor(v, 1);
        v += __shfl_xor(v, 2);
        v += __shfl_xor(v, 4);
        v += __shfl_xor(v, 8);
        v += __shfl_xor(v, 16);
        if (l31 == 0) {
            int rowq = (wb << 5) + (q & 3) + ((q >> 2) << 3) + (hi << 2);
            out[m0 + rowq] = v + wys[rowq][27] * wys[rowq][28];
        }
    }
#undef LOADT
#undef WRITET
}

extern "C" void kernel_launch(void* const* d_in, const int* in_sizes, int n_in,
                              void* d_out, int out_size, void* d_ws, size_t ws_size,
                              hipStream_t stream) {
    const float* x  = (const float*)d_in[0];
    const float* y  = (const float*)d_in[1];
    const float* U3 = (const float*)d_in[2];
    const float* U2 = (const float*)d_in[3];
    const float* U1 = (const float*)d_in[4];
    const float* W3 = (const float*)d_in[5];
    const float* W2 = (const float*)d_in[6];
    const float* W1 = (const float*)d_in[7];
    __hip_bfloat16* Bf = (__hip_bfloat16*)d_ws;   // 192 frags * 64 lanes * 8 bf16 * 2B = 196608 B

    build_B<<<NT * NSK, 64, 0, stream>>>(U3, U2, Bf);
    contract_k<<<2048, THREADS, 0, stream>>>(x, y, W3, W2, W1, U1, Bf, (float*)d_out);
}